// Round 10
// baseline (177.321 us; speedup 1.0000x reference)
//
#include <hip/hip_runtime.h>
#include <math.h>

#define NB 8
#define NC 512
#define NHW 1024
#define NG 32
#define CPG 16
#define QKV_C 1536
#define EPS 1e-5f
#define QSCALE 0.18033688011112042f   // 0.125 * log2(e)

typedef float  f32x4  __attribute__((ext_vector_type(4)));
typedef __bf16 bf16x8 __attribute__((ext_vector_type(8)));
typedef __bf16 bf16x4 __attribute__((ext_vector_type(4)));
typedef short  s16x4  __attribute__((ext_vector_type(4)));

__device__ __forceinline__ void gload_lds16(const void* g, void* l) {
    __builtin_amdgcn_global_load_lds(
        (const __attribute__((address_space(1))) void*)g,
        (__attribute__((address_space(3))) void*)l, 16, 0, 0);
}

// Drain this wave's outstanding global_load_lds DMA (vmcnt) before a
// __syncthreads() that publishes DMA-written LDS (R3 divergence fix).
__device__ __forceinline__ void dma_drain() {
    asm volatile("s_waitcnt vmcnt(0)" ::: "memory");
}

// 16x16x16 bf16 MFMA (K=16): A/B = 4 bf16 (2 VGPRs), C/D = 4 f32.
__device__ __forceinline__ f32x4 mfma16(bf16x4 a, bf16x4 b, f32x4 c) {
#if __has_builtin(__builtin_amdgcn_mfma_f32_16x16x16bf16_1k)
    return __builtin_amdgcn_mfma_f32_16x16x16bf16_1k(
        __builtin_bit_cast(s16x4, a), __builtin_bit_cast(s16x4, b), c, 0, 0, 0);
#else
    f32x4 d;
    asm volatile("v_mfma_f32_16x16x16_bf16 %0, %1, %2, %3"
                 : "=v"(d) : "v"(a), "v"(b), "v"(c));
    return d;
#endif
}

// ---------------- prep: GN1 stats (blocks 0..255) + weight cvt (256..1279) + zero gstat ----
__global__ __launch_bounds__(256) void prep_k(const float* __restrict__ x,
                                              float* __restrict__ mu,
                                              float* __restrict__ rinv,
                                              const float* __restrict__ w1,
                                              __bf16* __restrict__ d1,
                                              const float* __restrict__ w2,
                                              __bf16* __restrict__ d2,
                                              float* __restrict__ gstat) {
    const int bi = blockIdx.x;
    if (bi < 256) {
        const int grp = bi;
        const float4* p4 = (const float4*)(x + (size_t)grp * (CPG * NHW));
        float s = 0.f, s2 = 0.f;
        for (int i = threadIdx.x; i < CPG * NHW / 4; i += 256) {
            float4 v = p4[i];
            s  += v.x + v.y + v.z + v.w;
            s2 += v.x * v.x + v.y * v.y + v.z * v.z + v.w * v.w;
        }
        for (int off = 32; off > 0; off >>= 1) {
            s  += __shfl_down(s, off);
            s2 += __shfl_down(s2, off);
        }
        __shared__ float ls[4], ls2[4];
        const int wv = threadIdx.x >> 6;
        if ((threadIdx.x & 63) == 0) { ls[wv] = s; ls2[wv] = s2; }
        __syncthreads();
        if (threadIdx.x == 0) {
            float S = ls[0] + ls[1] + ls[2] + ls[3];
            float S2 = ls2[0] + ls2[1] + ls2[2] + ls2[3];
            const float inv = 1.f / (float)(CPG * NHW);
            float m = S * inv;
            float var = S2 * inv - m * m;
            mu[grp] = m;
            rinv[grp] = rsqrtf(var + EPS);
        }
        if (bi == 0 && threadIdx.x < 256) {
            gstat[threadIdx.x] = 0.f;
            gstat[threadIdx.x + 256] = 0.f;
        }
    } else {
        const int n1_4 = QKV_C * NC / 4;   // 196608
        const int i = (bi - 256) * 256 + threadIdx.x;
        const float4* s = (i < n1_4) ? (const float4*)w1 + i
                                     : (const float4*)w2 + (i - n1_4);
        bf16x4* d = (i < n1_4) ? (bf16x4*)d1 + i : (bf16x4*)d2 + (i - n1_4);
        float4 v = *s;
        bf16x4 o;
        o[0] = (__bf16)v.x; o[1] = (__bf16)v.y; o[2] = (__bf16)v.z; o[3] = (__bf16)v.w;
        *d = o;
    }
}

// ---------------- GN1 apply + transpose: hnT[b][n][c] bf16 ----------------
__global__ __launch_bounds__(256) void gn_apply_t_k(const float* __restrict__ x,
                                                    const float* __restrict__ mu,
                                                    const float* __restrict__ rinv,
                                                    const float* __restrict__ sc,
                                                    const float* __restrict__ bi,
                                                    __bf16* __restrict__ hnT) {
    __shared__ float T[64][65];
    const int tid = threadIdx.x;
    const int nb = blockIdx.x * 64, cb = blockIdx.y * 64, b = blockIdx.z;
    const int col = (tid & 15) * 4;
    const int rb = tid >> 4;
    #pragma unroll
    for (int rr = 0; rr < 4; rr++) {
        int cl = rr * 16 + rb;
        int c = cb + cl;
        int grp = b * NG + (c >> 4);
        float a = sc[c] * rinv[grp];
        float d = bi[c] - mu[grp] * a;
        float4 v4 = *(const float4*)&x[((size_t)(b * NC + c)) * NHW + nb + col];
        T[cl][col + 0] = v4.x * a + d;
        T[cl][col + 1] = v4.y * a + d;
        T[cl][col + 2] = v4.z * a + d;
        T[cl][col + 3] = v4.w * a + d;
    }
    __syncthreads();
    const int nl = tid >> 2;
    const int c0 = (tid & 3) * 16;
    bf16x8 o0, o1;
    #pragma unroll
    for (int i = 0; i < 8; i++) o0[i] = (__bf16)T[c0 + i][nl];
    #pragma unroll
    for (int i = 0; i < 8; i++) o1[i] = (__bf16)T[c0 + 8 + i][nl];
    __bf16* dst = hnT + ((size_t)(b * NHW + nb + nl)) * NC + cb + c0;
    *(bf16x8*)dst = o0;
    *(bf16x8*)(dst + 8) = o1;
}

// ---------------- MFMA GEMM core: 128x128 tile, BK=32, ping-pong LDS ----------------
__device__ __forceinline__ void mm_stage(const __bf16* __restrict__ W,
                                         const __bf16* __restrict__ Bm,
                                         int K, int m0, int n0, int k0,
                                         __bf16* As, __bf16* Bs) {
    const int tid = threadIdx.x;
    const int w = tid >> 6, lane = tid & 63;
    const int lr = lane >> 2, lk = (lane & 3) * 8;
    #pragma unroll
    for (int i = 0; i < 2; i++) {
        int rb = (w * 2 + i) * 16;
        gload_lds16(W  + (size_t)(m0 + rb + lr) * K + k0 + lk, As + rb * 32);
        gload_lds16(Bm + (size_t)(n0 + rb + lr) * K + k0 + lk, Bs + rb * 32);
    }
}

__device__ __forceinline__ void mm_core(const __bf16* __restrict__ W,
                                        const __bf16* __restrict__ Bm,
                                        int K, int m0, int n0,
                                        __bf16* As, __bf16* Bs,
                                        f32x4 (&acc)[4][4]) {
    const int tid = threadIdx.x;
    const int w = tid >> 6, lane = tid & 63;
    const int l15 = lane & 15, quad = lane >> 4;
    const int wm = (w & 1) * 64, wn = (w >> 1) * 64;
    const int nk = K >> 5;
    mm_stage(W, Bm, K, m0, n0, 0, As, Bs);
    for (int it = 0; it < nk; it++) {
        const int cur = (it & 1) * 4096;
        dma_drain();
        __syncthreads();
        if (it + 1 < nk)
            mm_stage(W, Bm, K, m0, n0, (it + 1) * 32, As + (4096 - cur), Bs + (4096 - cur));
        bf16x8 af[4], bfv[4];
        #pragma unroll
        for (int mi = 0; mi < 4; mi++)
            af[mi] = *(const bf16x8*)(As + cur + (wm + mi * 16 + l15) * 32 + quad * 8);
        #pragma unroll
        for (int ni = 0; ni < 4; ni++)
            bfv[ni] = *(const bf16x8*)(Bs + cur + (wn + ni * 16 + l15) * 32 + quad * 8);
        #pragma unroll
        for (int mi = 0; mi < 4; mi++)
            #pragma unroll
            for (int ni = 0; ni < 4; ni++)
                acc[mi][ni] = __builtin_amdgcn_mfma_f32_16x16x32_bf16(
                    af[mi], bfv[ni], acc[mi][ni], 0, 0, 0);
    }
}

// ---------------- QKV GEMM: qT[bh][n][64] (pre-scaled), kT[bh][n][64], v[bh][c][n] ----
__global__ __launch_bounds__(256) void qkv_gemm_k(const __bf16* __restrict__ W,
                                                  const __bf16* __restrict__ hnT,
                                                  const float* __restrict__ bias,
                                                  __bf16* __restrict__ qT,
                                                  __bf16* __restrict__ kT,
                                                  __bf16* __restrict__ v) {
    __shared__ __bf16 As[2 * 128 * 32];
    __shared__ __bf16 Bs[2 * 128 * 32];
    const int m0 = blockIdx.x * 128, n0 = blockIdx.y * 128, b = blockIdx.z;
    f32x4 acc[4][4] = {};
    mm_core(W, hnT + (size_t)b * NHW * NC, NC, m0, n0, As, Bs, acc);
    const int tid = threadIdx.x;
    const int w = tid >> 6, lane = tid & 63;
    const int l15 = lane & 15, quad = lane >> 4;
    const int wm = (w & 1) * 64, wn = (w >> 1) * 64;
    #pragma unroll
    for (int mi = 0; mi < 4; mi++) {
        const int mbase = m0 + wm + mi * 16 + quad * 4;   // 4-aligned; never straddles 64/192 bounds
        const f32x4 bb4 = *(const f32x4*)&bias[mbase];
        const int h = mbase / 192;
        const int rr = mbase - h * 192;
        const int bh = b * 8 + h;
        #pragma unroll
        for (int ni = 0; ni < 4; ni++) {
            const int n = n0 + wn + ni * 16 + l15;
            f32x4 a4 = acc[mi][ni];
            if (rr < 64) {
                bf16x4 o;
                #pragma unroll
                for (int r = 0; r < 4; r++) o[r] = (__bf16)((a4[r] + bb4[r]) * QSCALE);
                *(bf16x4*)&qT[((size_t)bh << 16) + n * 64 + rr] = o;
            } else if (rr < 128) {
                bf16x4 o;
                #pragma unroll
                for (int r = 0; r < 4; r++) o[r] = (__bf16)(a4[r] + bb4[r]);
                *(bf16x4*)&kT[((size_t)bh << 16) + n * 64 + (rr - 64)] = o;
            } else {
                #pragma unroll
                for (int r = 0; r < 4; r++)
                    v[((size_t)(bh * 64 + rr - 128 + r)) * NHW + n] = (__bf16)(a4[r] + bb4[r]);
            }
        }
    }
}

// ---------------- proj GEMM: 64x128 tile, 2 blocks/CU; projb bf16 + GN2 sums ----
__global__ __launch_bounds__(256) void proj_gemm_k(const __bf16* __restrict__ W,
                                                   const __bf16* __restrict__ aTin,
                                                   const float* __restrict__ bias,
                                                   __bf16* __restrict__ projb,
                                                   float* __restrict__ gstat) {
    __shared__ __bf16 As[2 * 64 * 32];    // 2 x 4 KB
    __shared__ __bf16 Bs[2 * 128 * 32];   // 2 x 8 KB
    const int m0 = blockIdx.x * 64, n0 = blockIdx.y * 128, b = blockIdx.z;
    const __bf16* Bm = aTin + (size_t)b * NHW * NC;
    const int tid = threadIdx.x;
    const int w = tid >> 6, lane = tid & 63;
    const int l15 = lane & 15, quad = lane >> 4;
    const int lr = lane >> 2, lk = (lane & 3) * 8;
    f32x4 acc[4][2] = {};
    {
        gload_lds16(W + (size_t)(m0 + w * 16 + lr) * NC + lk, As + (w * 16) * 32);
        #pragma unroll
        for (int i = 0; i < 2; i++) {
            int rb = w * 32 + i * 16;
            gload_lds16(Bm + (size_t)(n0 + rb + lr) * NC + lk, Bs + rb * 32);
        }
    }
    for (int it = 0; it < 16; it++) {
        const int curA = (it & 1) * 2048, curB = (it & 1) * 4096;
        dma_drain();
        __syncthreads();
        if (it + 1 < 16) {
            const int k0 = (it + 1) * 32;
            gload_lds16(W + (size_t)(m0 + w * 16 + lr) * NC + k0 + lk,
                        As + (2048 - curA) + (w * 16) * 32);
            #pragma unroll
            for (int i = 0; i < 2; i++) {
                int rb = w * 32 + i * 16;
                gload_lds16(Bm + (size_t)(n0 + rb + lr) * NC + k0 + lk,
                            Bs + (4096 - curB) + rb * 32);
            }
        }
        bf16x8 af[4], bfv[2];
        #pragma unroll
        for (int mi = 0; mi < 4; mi++)
            af[mi] = *(const bf16x8*)(As + curA + (mi * 16 + l15) * 32 + quad * 8);
        #pragma unroll
        for (int ni = 0; ni < 2; ni++)
            bfv[ni] = *(const bf16x8*)(Bs + curB + (w * 32 + ni * 16 + l15) * 32 + quad * 8);
        #pragma unroll
        for (int mi = 0; mi < 4; mi++)
            #pragma unroll
            for (int ni = 0; ni < 2; ni++)
                acc[mi][ni] = __builtin_amdgcn_mfma_f32_16x16x32_bf16(
                    af[mi], bfv[ni], acc[mi][ni], 0, 0, 0);
    }
    float bsum[4] = {}, bsq[4] = {};
    #pragma unroll
    for (int mi = 0; mi < 4; mi++) {
        #pragma unroll
        for (int r = 0; r < 4; r++) {
            int m = m0 + mi * 16 + quad * 4 + r;
            float bb = bias[m];
            #pragma unroll
            for (int ni = 0; ni < 2; ni++) {
                int n = n0 + w * 32 + ni * 16 + l15;
                float val = acc[mi][ni][r] + bb;
                projb[((size_t)(b * NC + m)) * NHW + n] = (__bf16)val;
                bsum[mi] += val;
                bsq[mi] += val * val;
            }
        }
    }
    #pragma unroll
    for (int mi = 0; mi < 4; mi++) {
        float s = bsum[mi], q = bsq[mi];
        #pragma unroll
        for (int off = 1; off < 64; off <<= 1) {
            s += __shfl_xor(s, off);
            q += __shfl_xor(q, off);
        }
        if (lane == 0) {
            int grp = b * NG + (m0 >> 4) + mi;
            atomicAdd(&gstat[grp], s);
            atomicAdd(&gstat[256 + grp], q);
        }
    }
}

// ---------------- MFMA flash attention: t64/s64 tiles, 4 blocks/CU ----------------
// grid (64 bh, 16 t-tiles of 64), 256 threads. Wave w owns t in [t0+16w, t0+16w+16).
// qT (pre-scaled): [bh][t][64]; kT: [bh][s][64]; v: [bh][c][s]; out aT: [b][t][512].
// 32 KB LDS (K dbuf 16 + V dbuf 16) + __launch_bounds__(256,4) -> 4 blocks/CU
// (16 waves/CU, vs 2 blocks since R5: occupancy is the stall cure, not per-wave ILP).
// PV = mfma(A=V, B=P): P's QK C-layout is the K16 B-frag; D is c-major (R9 epilogue).
__global__ __launch_bounds__(256, 4) void attn_k(const __bf16* __restrict__ qT,
                                                 const __bf16* __restrict__ kT,
                                                 const __bf16* __restrict__ vv,
                                                 __bf16* __restrict__ aT) {
    __shared__ __bf16 Kt[2 * 4096];   // 2 bufs x [ch][s64][32] = 16 KB
    __shared__ __bf16 Vt[2 * 4096];   // 2 bufs x [c][64] chunk-XOR swizzled = 16 KB
    const int tid = threadIdx.x;
    const int w = tid >> 6, lane = tid & 63;
    const int l15 = lane & 15, quad = lane >> 4;
    const int lr = lane >> 2, lk = (lane & 3) * 8;
    const int bh = blockIdx.x, t0 = blockIdx.y * 64;
    const __bf16* qb = qT + ((size_t)bh << 16);
    const __bf16* kb = kT + ((size_t)bh << 16);
    const __bf16* vb = vv + ((size_t)bh << 6) * NHW;
    const int xmask = l15 & 14;

    // Q fragments: B[n=t][k=c], t = t0 + w*16 + l15
    bf16x8 qfr[2];
    #pragma unroll
    for (int ch = 0; ch < 2; ch++)
        qfr[ch] = *(const bf16x8*)(qb + (size_t)(t0 + w * 16 + l15) * 64
                                   + ch * 32 + quad * 8);
    // stage K/V tile 0 into buffer 0: 16 DMA instrs, 4 per wave (R6-verified layout)
    #pragma unroll
    for (int i = 0; i < 4; i++) {
        int inst = w * 4 + i;
        if (inst < 8) {
            int ch = inst >> 2, sb = (inst & 3) * 16;
            gload_lds16(kb + (size_t)(sb + lr) * 64 + ch * 32 + lk,
                        Kt + ch * 2048 + sb * 32);
        } else {
            int ip = inst - 8;                  // 0..7, 8 c-rows each
            int c = ip * 8 + (lane >> 3);
            int m2 = (lane & 7) * 2;            // dst chunk pair
            gload_lds16(vb + (size_t)c * NHW + 4 * (m2 ^ (c & 14)),
                        Vt + ip * 512);
        }
    }
    float lp = 0.f;
    f32x4 Oacc[4] = {};   // [ci]: c = ci*16+quad*4+r, t = l15 (c-major D)

    for (int it = 0; it < 16; it++) {
        const int cur = (it & 1) * 4096;
        const int nxt = 4096 - cur;
        dma_drain();
        __syncthreads();
        if (it + 1 < 16) {
            const int s0 = (it + 1) * 64;
            #pragma unroll
            for (int i = 0; i < 4; i++) {
                int inst = w * 4 + i;
                if (inst < 8) {
                    int ch = inst >> 2, sb = (inst & 3) * 16;
                    gload_lds16(kb + (size_t)(s0 + sb + lr) * 64 + ch * 32 + lk,
                                Kt + nxt + ch * 2048 + sb * 32);
                } else {
                    int ip = inst - 8;
                    int c = ip * 8 + (lane >> 3);
                    int m2 = (lane & 7) * 2;
                    gload_lds16(vb + (size_t)c * NHW + s0 + 4 * (m2 ^ (c & 14)),
                                Vt + nxt + ip * 512);
                }
            }
        }
        // S^T: sacc[j], s-block j covers s in [16j,16j+16); lane: s=quad*4+r, t=l15
        f32x4 sacc[4] = {};
        #pragma unroll
        for (int ch = 0; ch < 2; ch++)
            #pragma unroll
            for (int j = 0; j < 4; j++) {
                bf16x8 kfr = *(const bf16x8*)(Kt + cur + ch * 2048
                                              + (j * 16 + l15) * 32 + quad * 8);
                sacc[j] = __builtin_amdgcn_mfma_f32_16x16x32_bf16(
                    kfr, qfr[ch], sacc[j], 0, 0, 0);
            }
        // P = exp2(S^T) in registers; lane holds P(s=quad*4+r, t=l15) = K16 B-frag
        bf16x4 pf[4];
        #pragma unroll
        for (int j = 0; j < 4; j++) {
            bf16x4 pk;
            #pragma unroll
            for (int r = 0; r < 4; r++) {
                float pv = __builtin_amdgcn_exp2f(sacc[j][r]);
                lp += pv;
                pk[r] = (__bf16)pv;
            }
            pf[j] = pk;
        }
        // O[c][t] += V[c][s] P[s][t]; V A-frag: c=ci*16+l15, s-chunk (jt*4+quad)^xmask
        #pragma unroll
        for (int jt = 0; jt < 4; jt++) {
            const __bf16* vbase = Vt + cur + (((jt * 4 + quad) ^ xmask) << 2);
            #pragma unroll
            for (int ci = 0; ci < 4; ci++) {
                bf16x4 vfr = *(const bf16x4*)(vbase + (ci * 16 + l15) * 64);
                Oacc[ci] = mfma16(vfr, pf[jt], Oacc[ci]);
            }
        }
    }
    const int b = bh >> 3, hh = bh & 7;
    float s = lp;
    s += __shfl_xor(s, 16);
    s += __shfl_xor(s, 32);          // every lane: full row-sum for its t = l15
    const float inv = 1.f / s;
    const int t = t0 + w * 16 + l15;
    __bf16* dst = aT + ((size_t)(b * NHW + t)) * NC + hh * 64;
    #pragma unroll
    for (int ci = 0; ci < 4; ci++) {
        bf16x4 o;
        #pragma unroll
        for (int r = 0; r < 4; r++) o[r] = (__bf16)(Oacc[ci][r] * inv);
        *(bf16x4*)(dst + ci * 16 + quad * 4) = o;
    }
}

// ---------------- final: out = x + GN2(projb), stats from gstat sums ----------------
__global__ __launch_bounds__(256) void final_k(const float* __restrict__ x,
                                               const __bf16* __restrict__ pb,
                                               const float* __restrict__ gstat,
                                               const float* __restrict__ sc,
                                               const float* __restrict__ bi,
                                               float* __restrict__ out) {
    const int i4 = blockIdx.x * 256 + threadIdx.x;
    const int c  = (i4 >> 8) & (NC - 1);
    const int b  = i4 >> 17;
    const int grp = b * NG + (c >> 4);
    const float inv = 1.f / (float)(CPG * NHW);
    const float m = gstat[grp] * inv;
    const float var = gstat[256 + grp] * inv - m * m;
    const float r = rsqrtf(var + EPS);
    const float a = sc[c] * r;
    const float d = bi[c] - m * a;
    float4 xv = ((const float4*)x)[i4];
    bf16x4 pv = ((const bf16x4*)pb)[i4];
    float4 o = make_float4(xv.x + (float)pv[0] * a + d, xv.y + (float)pv[1] * a + d,
                           xv.z + (float)pv[2] * a + d, xv.w + (float)pv[3] * a + d);
    ((float4*)out)[i4] = o;
}

extern "C" void kernel_launch(void* const* d_in, const int* in_sizes, int n_in,
                              void* d_out, int out_size, void* d_ws, size_t ws_size,
                              hipStream_t stream) {
    const float* x      = (const float*)d_in[0];
    const float* gn1_s  = (const float*)d_in[1];
    const float* gn1_b  = (const float*)d_in[2];
    const float* w_qkv  = (const float*)d_in[3];
    const float* b_qkv  = (const float*)d_in[4];
    const float* w_proj = (const float*)d_in[5];
    const float* b_proj = (const float*)d_in[6];
    const float* gn2_s  = (const float*)d_in[7];
    const float* gn2_b  = (const float*)d_in[8];
    float* out = (float*)d_out;

    char* p = (char*)d_ws;
    __bf16* hnT   = (__bf16*)p;           p += (size_t)8 * 1024 * 512 * 2;   // 8 MB
    __bf16* qT    = (__bf16*)p;           p += (size_t)64 * 1024 * 64 * 2;   // 8 MB
    __bf16* kT    = (__bf16*)p;           p += (size_t)64 * 1024 * 64 * 2;   // 8 MB
    __bf16* vB    = (__bf16*)p;           p += (size_t)64 * 64 * 1024 * 2;   // 8 MB
    __bf16* aT    = (__bf16*)p;           p += (size_t)8 * 1024 * 512 * 2;   // 8 MB
    __bf16* projb = (__bf16*)p;           p += (size_t)8 * 512 * 1024 * 2;   // 8 MB
    __bf16* wq    = (__bf16*)p;           p += (size_t)QKV_C * NC * 2;       // 1.5 MB
    __bf16* wp    = (__bf16*)p;           p += (size_t)NC * NC * 2;          // 0.5 MB
    float*  mu1   = (float*)p;            p += 256 * 4;
    float*  ri1   = (float*)p;            p += 256 * 4;
    float*  gstat = (float*)p;            p += 512 * 4;   // [0:256) sum, [256:512) sumsq

    prep_k<<<1280, 256, 0, stream>>>(x, mu1, ri1, w_qkv, wq, w_proj, wp, gstat);
    gn_apply_t_k<<<dim3(16, 8, 8), 256, 0, stream>>>(x, mu1, ri1, gn1_s, gn1_b, hnT);

    qkv_gemm_k<<<dim3(12, 8, 8), 256, 0, stream>>>(wq, hnT, b_qkv, qT, kT, vB);

    attn_k<<<dim3(64, 16), 256, 0, stream>>>(qT, kT, vB, aT);

    proj_gemm_k<<<dim3(8, 8, 8), 256, 0, stream>>>(wp, aT, b_proj, projb, gstat);

    final_k<<<4096, 256, 0, stream>>>(x, projb, gstat, gn2_s, gn2_b, out);
}

// Round 11
// 171.610 us; speedup vs baseline: 1.0333x; 1.0333x over previous
//
#include <hip/hip_runtime.h>
#include <math.h>

#define NB 8
#define NC 512
#define NHW 1024
#define NG 32
#define CPG 16
#define QKV_C 1536
#define EPS 1e-5f
#define QSCALE 0.18033688011112042f   // 0.125 * log2(e)

typedef float  f32x4  __attribute__((ext_vector_type(4)));
typedef __bf16 bf16x8 __attribute__((ext_vector_type(8)));
typedef __bf16 bf16x4 __attribute__((ext_vector_type(4)));
typedef short  s16x4  __attribute__((ext_vector_type(4)));

__device__ __forceinline__ void gload_lds16(const void* g, void* l) {
    __builtin_amdgcn_global_load_lds(
        (const __attribute__((address_space(1))) void*)g,
        (__attribute__((address_space(3))) void*)l, 16, 0, 0);
}

// Drain this wave's outstanding global_load_lds DMA (vmcnt) before a
// __syncthreads() that publishes DMA-written LDS (R3 divergence fix).
__device__ __forceinline__ void dma_drain() {
    asm volatile("s_waitcnt vmcnt(0)" ::: "memory");
}

// 16x16x16 bf16 MFMA (K=16): A/B = 4 bf16 (2 VGPRs), C/D = 4 f32.
__device__ __forceinline__ f32x4 mfma16(bf16x4 a, bf16x4 b, f32x4 c) {
#if __has_builtin(__builtin_amdgcn_mfma_f32_16x16x16bf16_1k)
    return __builtin_amdgcn_mfma_f32_16x16x16bf16_1k(
        __builtin_bit_cast(s16x4, a), __builtin_bit_cast(s16x4, b), c, 0, 0, 0);
#else
    f32x4 d;
    asm volatile("v_mfma_f32_16x16x16_bf16 %0, %1, %2, %3"
                 : "=v"(d) : "v"(a), "v"(b), "v"(c));
    return d;
#endif
}

// ---------------- prep: GN1 stats (blocks 0..255) + weight cvt (256..1279) + zero gstat ----
__global__ __launch_bounds__(256) void prep_k(const float* __restrict__ x,
                                              float* __restrict__ mu,
                                              float* __restrict__ rinv,
                                              const float* __restrict__ w1,
                                              __bf16* __restrict__ d1,
                                              const float* __restrict__ w2,
                                              __bf16* __restrict__ d2,
                                              float* __restrict__ gstat) {
    const int bi = blockIdx.x;
    if (bi < 256) {
        const int grp = bi;
        const float4* p4 = (const float4*)(x + (size_t)grp * (CPG * NHW));
        float s = 0.f, s2 = 0.f;
        for (int i = threadIdx.x; i < CPG * NHW / 4; i += 256) {
            float4 v = p4[i];
            s  += v.x + v.y + v.z + v.w;
            s2 += v.x * v.x + v.y * v.y + v.z * v.z + v.w * v.w;
        }
        for (int off = 32; off > 0; off >>= 1) {
            s  += __shfl_down(s, off);
            s2 += __shfl_down(s2, off);
        }
        __shared__ float ls[4], ls2[4];
        const int wv = threadIdx.x >> 6;
        if ((threadIdx.x & 63) == 0) { ls[wv] = s; ls2[wv] = s2; }
        __syncthreads();
        if (threadIdx.x == 0) {
            float S = ls[0] + ls[1] + ls[2] + ls[3];
            float S2 = ls2[0] + ls2[1] + ls2[2] + ls2[3];
            const float inv = 1.f / (float)(CPG * NHW);
            float m = S * inv;
            float var = S2 * inv - m * m;
            mu[grp] = m;
            rinv[grp] = rsqrtf(var + EPS);
        }
        if (bi == 0 && threadIdx.x < 256) {
            gstat[threadIdx.x] = 0.f;
            gstat[threadIdx.x + 256] = 0.f;
        }
    } else {
        const int n1_4 = QKV_C * NC / 4;   // 196608
        const int i = (bi - 256) * 256 + threadIdx.x;
        const float4* s = (i < n1_4) ? (const float4*)w1 + i
                                     : (const float4*)w2 + (i - n1_4);
        bf16x4* d = (i < n1_4) ? (bf16x4*)d1 + i : (bf16x4*)d2 + (i - n1_4);
        float4 v = *s;
        bf16x4 o;
        o[0] = (__bf16)v.x; o[1] = (__bf16)v.y; o[2] = (__bf16)v.z; o[3] = (__bf16)v.w;
        *d = o;
    }
}

// ---------------- GN1 apply + transpose: hnT[b][n][c] bf16 ----------------
__global__ __launch_bounds__(256) void gn_apply_t_k(const float* __restrict__ x,
                                                    const float* __restrict__ mu,
                                                    const float* __restrict__ rinv,
                                                    const float* __restrict__ sc,
                                                    const float* __restrict__ bi,
                                                    __bf16* __restrict__ hnT) {
    __shared__ float T[64][65];
    const int tid = threadIdx.x;
    const int nb = blockIdx.x * 64, cb = blockIdx.y * 64, b = blockIdx.z;
    const int col = (tid & 15) * 4;
    const int rb = tid >> 4;
    #pragma unroll
    for (int rr = 0; rr < 4; rr++) {
        int cl = rr * 16 + rb;
        int c = cb + cl;
        int grp = b * NG + (c >> 4);
        float a = sc[c] * rinv[grp];
        float d = bi[c] - mu[grp] * a;
        float4 v4 = *(const float4*)&x[((size_t)(b * NC + c)) * NHW + nb + col];
        T[cl][col + 0] = v4.x * a + d;
        T[cl][col + 1] = v4.y * a + d;
        T[cl][col + 2] = v4.z * a + d;
        T[cl][col + 3] = v4.w * a + d;
    }
    __syncthreads();
    const int nl = tid >> 2;
    const int c0 = (tid & 3) * 16;
    bf16x8 o0, o1;
    #pragma unroll
    for (int i = 0; i < 8; i++) o0[i] = (__bf16)T[c0 + i][nl];
    #pragma unroll
    for (int i = 0; i < 8; i++) o1[i] = (__bf16)T[c0 + 8 + i][nl];
    __bf16* dst = hnT + ((size_t)(b * NHW + nb + nl)) * NC + cb + c0;
    *(bf16x8*)dst = o0;
    *(bf16x8*)(dst + 8) = o1;
}

// ---------------- MFMA GEMM core: 128x128 tile, BK=32, ping-pong LDS ----------------
__device__ __forceinline__ void mm_stage(const __bf16* __restrict__ W,
                                         const __bf16* __restrict__ Bm,
                                         int K, int m0, int n0, int k0,
                                         __bf16* As, __bf16* Bs) {
    const int tid = threadIdx.x;
    const int w = tid >> 6, lane = tid & 63;
    const int lr = lane >> 2, lk = (lane & 3) * 8;
    #pragma unroll
    for (int i = 0; i < 2; i++) {
        int rb = (w * 2 + i) * 16;
        gload_lds16(W  + (size_t)(m0 + rb + lr) * K + k0 + lk, As + rb * 32);
        gload_lds16(Bm + (size_t)(n0 + rb + lr) * K + k0 + lk, Bs + rb * 32);
    }
}

__device__ __forceinline__ void mm_core(const __bf16* __restrict__ W,
                                        const __bf16* __restrict__ Bm,
                                        int K, int m0, int n0,
                                        __bf16* As, __bf16* Bs,
                                        f32x4 (&acc)[4][4]) {
    const int tid = threadIdx.x;
    const int w = tid >> 6, lane = tid & 63;
    const int l15 = lane & 15, quad = lane >> 4;
    const int wm = (w & 1) * 64, wn = (w >> 1) * 64;
    const int nk = K >> 5;
    mm_stage(W, Bm, K, m0, n0, 0, As, Bs);
    for (int it = 0; it < nk; it++) {
        const int cur = (it & 1) * 4096;
        dma_drain();
        __syncthreads();
        if (it + 1 < nk)
            mm_stage(W, Bm, K, m0, n0, (it + 1) * 32, As + (4096 - cur), Bs + (4096 - cur));
        bf16x8 af[4], bfv[4];
        #pragma unroll
        for (int mi = 0; mi < 4; mi++)
            af[mi] = *(const bf16x8*)(As + cur + (wm + mi * 16 + l15) * 32 + quad * 8);
        #pragma unroll
        for (int ni = 0; ni < 4; ni++)
            bfv[ni] = *(const bf16x8*)(Bs + cur + (wn + ni * 16 + l15) * 32 + quad * 8);
        #pragma unroll
        for (int mi = 0; mi < 4; mi++)
            #pragma unroll
            for (int ni = 0; ni < 4; ni++)
                acc[mi][ni] = __builtin_amdgcn_mfma_f32_16x16x32_bf16(
                    af[mi], bfv[ni], acc[mi][ni], 0, 0, 0);
    }
}

// ---------------- QKV GEMM: qT[bh][n][64] (pre-scaled), kT[bh][n][64], v[bh][c][n] ----
__global__ __launch_bounds__(256) void qkv_gemm_k(const __bf16* __restrict__ W,
                                                  const __bf16* __restrict__ hnT,
                                                  const float* __restrict__ bias,
                                                  __bf16* __restrict__ qT,
                                                  __bf16* __restrict__ kT,
                                                  __bf16* __restrict__ v) {
    __shared__ __bf16 As[2 * 128 * 32];
    __shared__ __bf16 Bs[2 * 128 * 32];
    const int m0 = blockIdx.x * 128, n0 = blockIdx.y * 128, b = blockIdx.z;
    f32x4 acc[4][4] = {};
    mm_core(W, hnT + (size_t)b * NHW * NC, NC, m0, n0, As, Bs, acc);
    const int tid = threadIdx.x;
    const int w = tid >> 6, lane = tid & 63;
    const int l15 = lane & 15, quad = lane >> 4;
    const int wm = (w & 1) * 64, wn = (w >> 1) * 64;
    #pragma unroll
    for (int mi = 0; mi < 4; mi++) {
        const int mbase = m0 + wm + mi * 16 + quad * 4;   // 4-aligned; never straddles 64/192 bounds
        const f32x4 bb4 = *(const f32x4*)&bias[mbase];
        const int h = mbase / 192;
        const int rr = mbase - h * 192;
        const int bh = b * 8 + h;
        #pragma unroll
        for (int ni = 0; ni < 4; ni++) {
            const int n = n0 + wn + ni * 16 + l15;
            f32x4 a4 = acc[mi][ni];
            if (rr < 64) {
                bf16x4 o;
                #pragma unroll
                for (int r = 0; r < 4; r++) o[r] = (__bf16)((a4[r] + bb4[r]) * QSCALE);
                *(bf16x4*)&qT[((size_t)bh << 16) + n * 64 + rr] = o;
            } else if (rr < 128) {
                bf16x4 o;
                #pragma unroll
                for (int r = 0; r < 4; r++) o[r] = (__bf16)(a4[r] + bb4[r]);
                *(bf16x4*)&kT[((size_t)bh << 16) + n * 64 + (rr - 64)] = o;
            } else {
                #pragma unroll
                for (int r = 0; r < 4; r++)
                    v[((size_t)(bh * 64 + rr - 128 + r)) * NHW + n] = (__bf16)(a4[r] + bb4[r]);
            }
        }
    }
}

// ---------------- proj GEMM: 64x128 tile, 2 blocks/CU; projb bf16 + GN2 sums ----
__global__ __launch_bounds__(256) void proj_gemm_k(const __bf16* __restrict__ W,
                                                   const __bf16* __restrict__ aTin,
                                                   const float* __restrict__ bias,
                                                   __bf16* __restrict__ projb,
                                                   float* __restrict__ gstat) {
    __shared__ __bf16 As[2 * 64 * 32];    // 2 x 4 KB
    __shared__ __bf16 Bs[2 * 128 * 32];   // 2 x 8 KB
    const int m0 = blockIdx.x * 64, n0 = blockIdx.y * 128, b = blockIdx.z;
    const __bf16* Bm = aTin + (size_t)b * NHW * NC;
    const int tid = threadIdx.x;
    const int w = tid >> 6, lane = tid & 63;
    const int l15 = lane & 15, quad = lane >> 4;
    const int lr = lane >> 2, lk = (lane & 3) * 8;
    f32x4 acc[4][2] = {};
    {
        gload_lds16(W + (size_t)(m0 + w * 16 + lr) * NC + lk, As + (w * 16) * 32);
        #pragma unroll
        for (int i = 0; i < 2; i++) {
            int rb = w * 32 + i * 16;
            gload_lds16(Bm + (size_t)(n0 + rb + lr) * NC + lk, Bs + rb * 32);
        }
    }
    for (int it = 0; it < 16; it++) {
        const int curA = (it & 1) * 2048, curB = (it & 1) * 4096;
        dma_drain();
        __syncthreads();
        if (it + 1 < 16) {
            const int k0 = (it + 1) * 32;
            gload_lds16(W + (size_t)(m0 + w * 16 + lr) * NC + k0 + lk,
                        As + (2048 - curA) + (w * 16) * 32);
            #pragma unroll
            for (int i = 0; i < 2; i++) {
                int rb = w * 32 + i * 16;
                gload_lds16(Bm + (size_t)(n0 + rb + lr) * NC + k0 + lk,
                            Bs + (4096 - curB) + rb * 32);
            }
        }
        bf16x8 af[4], bfv[2];
        #pragma unroll
        for (int mi = 0; mi < 4; mi++)
            af[mi] = *(const bf16x8*)(As + curA + (mi * 16 + l15) * 32 + quad * 8);
        #pragma unroll
        for (int ni = 0; ni < 2; ni++)
            bfv[ni] = *(const bf16x8*)(Bs + curB + (w * 32 + ni * 16 + l15) * 32 + quad * 8);
        #pragma unroll
        for (int mi = 0; mi < 4; mi++)
            #pragma unroll
            for (int ni = 0; ni < 2; ni++)
                acc[mi][ni] = __builtin_amdgcn_mfma_f32_16x16x32_bf16(
                    af[mi], bfv[ni], acc[mi][ni], 0, 0, 0);
    }
    float bsum[4] = {}, bsq[4] = {};
    #pragma unroll
    for (int mi = 0; mi < 4; mi++) {
        #pragma unroll
        for (int r = 0; r < 4; r++) {
            int m = m0 + mi * 16 + quad * 4 + r;
            float bb = bias[m];
            #pragma unroll
            for (int ni = 0; ni < 2; ni++) {
                int n = n0 + w * 32 + ni * 16 + l15;
                float val = acc[mi][ni][r] + bb;
                projb[((size_t)(b * NC + m)) * NHW + n] = (__bf16)val;
                bsum[mi] += val;
                bsq[mi] += val * val;
            }
        }
    }
    #pragma unroll
    for (int mi = 0; mi < 4; mi++) {
        float s = bsum[mi], q = bsq[mi];
        #pragma unroll
        for (int off = 1; off < 64; off <<= 1) {
            s += __shfl_xor(s, off);
            q += __shfl_xor(q, off);
        }
        if (lane == 0) {
            int grp = b * NG + (m0 >> 4) + mi;
            atomicAdd(&gstat[grp], s);
            atomicAdd(&gstat[256 + grp], q);
        }
    }
}

// ---------------- MFMA flash attention: R9 winner (t128/s128, operand-swap PV) ----------------
// grid (64 bh, 8 q-tiles of 128), 256 threads. Wave w owns t in [t0+32w, t0+32w+32).
// qT (pre-scaled): [bh][t][64]; kT: [bh][s][64]; v: [bh][c][s]; out aT: [b][t][512].
// Per iter: all 8 s-blocks' S^T (32 indep QK MFMAs) -> 64 exp2 -> 64 PV MFMAs.
// PV uses mfma(A=V, B=P): P's QK C-layout (lane: s=quad*4+r, t=l15) IS the K16
// B-fragment; D comes out c-major so the epilogue is b64 stores, no shuffle bcast.
// NOTE (R10 post-mortem): t64/s64 @4 blocks/CU regressed — ILP between barriers
// beats occupancy here; grid is structurally 512 blocks and that is optimal.
__global__ __launch_bounds__(256, 2) void attn_k(const __bf16* __restrict__ qT,
                                                 const __bf16* __restrict__ kT,
                                                 const __bf16* __restrict__ vv,
                                                 __bf16* __restrict__ aT) {
    __shared__ __bf16 Kt[2 * 8192];   // 2 bufs x [ch][s128][32] = 32 KB
    __shared__ __bf16 Vt[2 * 8192];   // 2 bufs x [c][128] chunk-XOR swizzled = 32 KB
    const int tid = threadIdx.x;
    const int w = tid >> 6, lane = tid & 63;
    const int l15 = lane & 15, quad = lane >> 4;
    const int lr = lane >> 2, lk = (lane & 3) * 8;
    const int bh = blockIdx.x, t0 = blockIdx.y * 128;
    const __bf16* qb = qT + ((size_t)bh << 16);
    const __bf16* kb = kT + ((size_t)bh << 16);
    const __bf16* vb = vv + ((size_t)bh << 6) * NHW;
    const int xmask = l15 & 14;

    // Q fragments in registers: B[n=t][k=c], t = t0+w*32+tb*16+l15
    bf16x8 qfr[2][2];
    #pragma unroll
    for (int tb = 0; tb < 2; tb++)
        #pragma unroll
        for (int ch = 0; ch < 2; ch++)
            qfr[tb][ch] = *(const bf16x8*)(qb + (size_t)(t0 + w * 32 + tb * 16 + l15) * 64
                                           + ch * 32 + quad * 8);
    // stage K/V tile 0 into buffer 0: 32 DMA instrs, 8 per wave
    #pragma unroll
    for (int i = 0; i < 8; i++) {
        int inst = w * 8 + i;
        if (inst < 16) {
            int ch = inst >> 3, sb = (inst & 7) * 16;
            gload_lds16(kb + (size_t)(sb + lr) * 64 + ch * 32 + lk,
                        Kt + ch * 4096 + sb * 32);
        } else {
            int ip = inst - 16;                 // 0..15, 4 c-rows each
            int c = ip * 4 + (lane >> 4);
            int m2 = (lane & 15) * 2;           // dst chunk pair
            gload_lds16(vb + (size_t)c * NHW + 4 * (m2 ^ (c & 14)),
                        Vt + ip * 512);
        }
    }
    float lp[2] = {0.f, 0.f};
    f32x4 Oacc[2][4] = {};   // [tb][ci]: c = ci*16+quad*4+r, t = l15 (c-major D)

    for (int it = 0; it < 8; it++) {
        const int cur = (it & 1) * 8192;
        const int nxt = 8192 - cur;
        dma_drain();
        __syncthreads();
        if (it + 1 < 8) {
            const int s0 = (it + 1) * 128;
            #pragma unroll
            for (int i = 0; i < 8; i++) {
                int inst = w * 8 + i;
                if (inst < 16) {
                    int ch = inst >> 3, sb = (inst & 7) * 16;
                    gload_lds16(kb + (size_t)(s0 + sb + lr) * 64 + ch * 32 + lk,
                                Kt + nxt + ch * 4096 + sb * 32);
                } else {
                    int ip = inst - 16;
                    int c = ip * 4 + (lane >> 4);
                    int m2 = (lane & 15) * 2;
                    gload_lds16(vb + (size_t)c * NHW + s0 + 4 * (m2 ^ (c & 14)),
                                Vt + nxt + ip * 512);
                }
            }
        }
        // S^T: sacc[tb][j], s-block j covers s in [16j,16j+16), lane: s=quad*4+r, t=l15
        f32x4 sacc[2][8] = {};
        #pragma unroll
        for (int ch = 0; ch < 2; ch++)
            #pragma unroll
            for (int j = 0; j < 8; j++) {
                bf16x8 kfr = *(const bf16x8*)(Kt + cur + ch * 4096
                                              + (j * 16 + l15) * 32 + quad * 8);
                sacc[0][j] = __builtin_amdgcn_mfma_f32_16x16x32_bf16(
                    kfr, qfr[0][ch], sacc[0][j], 0, 0, 0);
                sacc[1][j] = __builtin_amdgcn_mfma_f32_16x16x32_bf16(
                    kfr, qfr[1][ch], sacc[1][j], 0, 0, 0);
            }
        // P = exp2(S^T) in registers; lane holds P(s=quad*4+j_r, t=l15) = K16 B-frag
        bf16x4 pf[2][8];
        #pragma unroll
        for (int tb = 0; tb < 2; tb++)
            #pragma unroll
            for (int j = 0; j < 8; j++) {
                bf16x4 pk;
                #pragma unroll
                for (int r = 0; r < 4; r++) {
                    float pv = __builtin_amdgcn_exp2f(sacc[tb][j][r]);
                    lp[tb] += pv;
                    pk[r] = (__bf16)pv;
                }
                pf[tb][j] = pk;
            }
        // O[c][t] += V[c][s] P[s][t]; V A-frag: c=ci*16+l15, s-chunk (jt*4+quad)^xmask
        #pragma unroll
        for (int jt = 0; jt < 8; jt++) {
            const __bf16* vbase = Vt + cur + ((((jt * 4 + quad)) ^ xmask) << 2);
            #pragma unroll
            for (int ci = 0; ci < 4; ci++) {
                bf16x4 vfr = *(const bf16x4*)(vbase + (ci * 16 + l15) * 128);
                Oacc[0][ci] = mfma16(vfr, pf[0][jt], Oacc[0][ci]);
                Oacc[1][ci] = mfma16(vfr, pf[1][jt], Oacc[1][ci]);
            }
        }
    }
    const int b = bh >> 3, hh = bh & 7;
    #pragma unroll
    for (int tb = 0; tb < 2; tb++) {
        float s = lp[tb];
        s += __shfl_xor(s, 16);
        s += __shfl_xor(s, 32);          // every lane: full row-sum for its t = l15
        const float inv = 1.f / s;
        const int t = t0 + w * 32 + tb * 16 + l15;
        __bf16* dst = aT + ((size_t)(b * NHW + t)) * NC + hh * 64;
        #pragma unroll
        for (int ci = 0; ci < 4; ci++) {
            bf16x4 o;
            #pragma unroll
            for (int r = 0; r < 4; r++) o[r] = (__bf16)(Oacc[tb][ci][r] * inv);
            *(bf16x4*)(dst + ci * 16 + quad * 4) = o;
        }
    }
}

// ---------------- final: out = x + GN2(projb), stats from gstat sums ----------------
__global__ __launch_bounds__(256) void final_k(const float* __restrict__ x,
                                               const __bf16* __restrict__ pb,
                                               const float* __restrict__ gstat,
                                               const float* __restrict__ sc,
                                               const float* __restrict__ bi,
                                               float* __restrict__ out) {
    const int i4 = blockIdx.x * 256 + threadIdx.x;
    const int c  = (i4 >> 8) & (NC - 1);
    const int b  = i4 >> 17;
    const int grp = b * NG + (c >> 4);
    const float inv = 1.f / (float)(CPG * NHW);
    const float m = gstat[grp] * inv;
    const float var = gstat[256 + grp] * inv - m * m;
    const float r = rsqrtf(var + EPS);
    const float a = sc[c] * r;
    const float d = bi[c] - m * a;
    float4 xv = ((const float4*)x)[i4];
    bf16x4 pv = ((const bf16x4*)pb)[i4];
    float4 o = make_float4(xv.x + (float)pv[0] * a + d, xv.y + (float)pv[1] * a + d,
                           xv.z + (float)pv[2] * a + d, xv.w + (float)pv[3] * a + d);
    ((float4*)out)[i4] = o;
}

extern "C" void kernel_launch(void* const* d_in, const int* in_sizes, int n_in,
                              void* d_out, int out_size, void* d_ws, size_t ws_size,
                              hipStream_t stream) {
    const float* x      = (const float*)d_in[0];
    const float* gn1_s  = (const float*)d_in[1];
    const float* gn1_b  = (const float*)d_in[2];
    const float* w_qkv  = (const float*)d_in[3];
    const float* b_qkv  = (const float*)d_in[4];
    const float* w_proj = (const float*)d_in[5];
    const float* b_proj = (const float*)d_in[6];
    const float* gn2_s  = (const float*)d_in[7];
    const float* gn2_b  = (const float*)d_in[8];
    float* out = (float*)d_out;

    char* p = (char*)d_ws;
    __bf16* hnT   = (__bf16*)p;           p += (size_t)8 * 1024 * 512 * 2;   // 8 MB
    __bf16* qT    = (__bf16*)p;           p += (size_t)64 * 1024 * 64 * 2;   // 8 MB
    __bf16* kT    = (__bf16*)p;           p += (size_t)64 * 1024 * 64 * 2;   // 8 MB
    __bf16* vB    = (__bf16*)p;           p += (size_t)64 * 64 * 1024 * 2;   // 8 MB
    __bf16* aT    = (__bf16*)p;           p += (size_t)8 * 1024 * 512 * 2;   // 8 MB
    __bf16* projb = (__bf16*)p;           p += (size_t)8 * 512 * 1024 * 2;   // 8 MB
    __bf16* wq    = (__bf16*)p;           p += (size_t)QKV_C * NC * 2;       // 1.5 MB
    __bf16* wp    = (__bf16*)p;           p += (size_t)NC * NC * 2;          // 0.5 MB
    float*  mu1   = (float*)p;            p += 256 * 4;
    float*  ri1   = (float*)p;            p += 256 * 4;
    float*  gstat = (float*)p;            p += 512 * 4;   // [0:256) sum, [256:512) sumsq

    prep_k<<<1280, 256, 0, stream>>>(x, mu1, ri1, w_qkv, wq, w_proj, wp, gstat);
    gn_apply_t_k<<<dim3(16, 8, 8), 256, 0, stream>>>(x, mu1, ri1, gn1_s, gn1_b, hnT);

    qkv_gemm_k<<<dim3(12, 8, 8), 256, 0, stream>>>(wq, hnT, b_qkv, qT, kT, vB);

    attn_k<<<dim3(64, 8), 256, 0, stream>>>(qT, kT, vB, aT);

    proj_gemm_k<<<dim3(8, 8, 8), 256, 0, stream>>>(wp, aT, b_proj, projb, gstat);

    final_k<<<4096, 256, 0, stream>>>(x, projb, gstat, gn2_s, gn2_b, out);
}